// Round 1
// baseline (273.026 us; speedup 1.0000x reference)
//
#include <hip/hip_runtime.h>
#include <hip/hip_bf16.h>

// CIN forward: B=2048, F=32, DIM=64, layers (128,128)
// out[b, 0:64]   = sum_d relu(W0 @ z0 + b0)[64:128, d]
// out[b, 64:192] = sum_d relu(W1 @ z1 + b1)[0:128, d]
// z0[h*32+m, d] = x[h,d]*x[m,d]   (h,m in [0,32))
// z1[h*32+m, d] = h1[h,d]*x[m,d]  (h in [0,64), m in [0,32)), h1 = layer0 rows 0..63

#define BATCH 2048
#define FSZ   32
#define DIM   64
#define K0    1024
#define K1    2048
#define OUTC  192

#define W0_ELEMS (128 * K0)   // 131072
#define W1_ELEMS (128 * K1)   // 262144

typedef __bf16 v8bf __attribute__((ext_vector_type(8)));
typedef float  v4f  __attribute__((ext_vector_type(4)));

#define XT_PITCH 40   // bf16 elems per row; 80B rows -> 16B-aligned b128, <=2-way banks
#define HT_PITCH 68   // 136B rows -> conflict-free u16 scalar reads across col lanes

__global__ void convert_w_kernel(const float* __restrict__ W0,
                                 const float* __restrict__ W1,
                                 __bf16* __restrict__ wbf) {
    int i = blockIdx.x * blockDim.x + threadIdx.x;
    if (i < W0_ELEMS) {
        wbf[i] = (__bf16)W0[i];
    } else {
        int j = i - W0_ELEMS;
        if (j < W1_ELEMS) wbf[W0_ELEMS + j] = (__bf16)W1[j];
    }
}

__global__ __launch_bounds__(256) void cin_kernel(
    const float* __restrict__ X,    // (B, 32, 64) fp32
    const float* __restrict__ b0,   // (128,)
    const float* __restrict__ b1,   // (128,)
    const __bf16* __restrict__ Wbf, // W0bf [128][1024] then W1bf [128][2048]
    float* __restrict__ out)        // (B, 192) fp32
{
    __shared__ __bf16 xT[DIM * XT_PITCH];   // xT[d][m] = x[m][d]
    __shared__ __bf16 h1T[DIM * HT_PITCH];  // h1T[d][h] = h1[h][d]

    const int b    = blockIdx.x;
    const int tid  = threadIdx.x;
    const int wave = tid >> 6;
    const int lane = tid & 63;
    const int quad = lane >> 4;
    const int col  = lane & 15;

    // ---- stage x -> LDS (transposed, bf16) ----
    const float* xb = X + (size_t)b * (FSZ * DIM);
    #pragma unroll
    for (int i = tid; i < FSZ * DIM; i += 256) {
        int m = i >> 6, d = i & 63;
        xT[d * XT_PITCH + m] = (__bf16)xb[i];
    }
    __syncthreads();

    // K-invariant vector part of B-fragments: xv[t][j] = x[quad*8+j][16t+col]
    float xv[4][8];
    #pragma unroll
    for (int t = 0; t < 4; ++t) {
        v8bf xvec = *(const v8bf*)(&xT[(16 * t + col) * XT_PITCH + quad * 8]);
        #pragma unroll
        for (int j = 0; j < 8; ++j) xv[t][j] = (float)xvec[j];
    }

    const int arow = wave * 32 + col;  // A-operand row for r=0 (r=1 adds 16)

    // ================= layer 0 =================
    v4f acc[2][4];
    #pragma unroll
    for (int r = 0; r < 2; ++r)
        #pragma unroll
        for (int t = 0; t < 4; ++t) acc[r][t] = (v4f)0.0f;

    const __bf16* W0bf = Wbf;
    for (int ks = 0; ks < 32; ++ks) {
        v8bf a0 = *(const v8bf*)(&W0bf[(size_t)arow * K0 + ks * 32 + quad * 8]);
        v8bf a1 = *(const v8bf*)(&W0bf[(size_t)(arow + 16) * K0 + ks * 32 + quad * 8]);
        v8bf bfr[4];
        #pragma unroll
        for (int t = 0; t < 4; ++t) {
            float s = (float)xT[(16 * t + col) * XT_PITCH + ks];
            #pragma unroll
            for (int j = 0; j < 8; ++j) bfr[t][j] = (__bf16)(s * xv[t][j]);
        }
        #pragma unroll
        for (int t = 0; t < 4; ++t) {
            acc[0][t] = __builtin_amdgcn_mfma_f32_16x16x32_bf16(a0, bfr[t], acc[0][t], 0, 0, 0);
            acc[1][t] = __builtin_amdgcn_mfma_f32_16x16x32_bf16(a1, bfr[t], acc[1][t], 0, 0, 0);
        }
    }

    // ---- epilogue 0: rows 0..63 -> h1T (LDS); rows 64..127 -> out[b, o-64] ----
    #pragma unroll
    for (int r = 0; r < 2; ++r) {
        const int obase = wave * 32 + r * 16 + quad * 4;
        if (obase < 64) {
            #pragma unroll
            for (int reg = 0; reg < 4; ++reg) {
                float bias = b0[obase + reg];
                #pragma unroll
                for (int t = 0; t < 4; ++t) {
                    float v = acc[r][t][reg] + bias;
                    v = v > 0.0f ? v : 0.0f;
                    h1T[(16 * t + col) * HT_PITCH + obase + reg] = (__bf16)v;
                }
            }
        } else {
            #pragma unroll
            for (int reg = 0; reg < 4; ++reg) {
                float bias = b0[obase + reg];
                float s = 0.0f;
                #pragma unroll
                for (int t = 0; t < 4; ++t) {
                    float v = acc[r][t][reg] + bias;
                    s += (v > 0.0f ? v : 0.0f);
                }
                s += __shfl_xor(s, 1);
                s += __shfl_xor(s, 2);
                s += __shfl_xor(s, 4);
                s += __shfl_xor(s, 8);
                if (col == 0) out[(size_t)b * OUTC + (obase + reg - 64)] = s;
            }
        }
    }
    __syncthreads();

    // ================= layer 1 =================
    #pragma unroll
    for (int r = 0; r < 2; ++r)
        #pragma unroll
        for (int t = 0; t < 4; ++t) acc[r][t] = (v4f)0.0f;

    const __bf16* W1bf = Wbf + W0_ELEMS;
    for (int ks = 0; ks < 64; ++ks) {
        v8bf a0 = *(const v8bf*)(&W1bf[(size_t)arow * K1 + ks * 32 + quad * 8]);
        v8bf a1 = *(const v8bf*)(&W1bf[(size_t)(arow + 16) * K1 + ks * 32 + quad * 8]);
        v8bf bfr[4];
        #pragma unroll
        for (int t = 0; t < 4; ++t) {
            float s = (float)h1T[(16 * t + col) * HT_PITCH + ks];
            #pragma unroll
            for (int j = 0; j < 8; ++j) bfr[t][j] = (__bf16)(s * xv[t][j]);
        }
        #pragma unroll
        for (int t = 0; t < 4; ++t) {
            acc[0][t] = __builtin_amdgcn_mfma_f32_16x16x32_bf16(a0, bfr[t], acc[0][t], 0, 0, 0);
            acc[1][t] = __builtin_amdgcn_mfma_f32_16x16x32_bf16(a1, bfr[t], acc[1][t], 0, 0, 0);
        }
    }

    // ---- epilogue 1: all 128 rows -> out[b, 64+o] ----
    #pragma unroll
    for (int r = 0; r < 2; ++r) {
        const int obase = wave * 32 + r * 16 + quad * 4;
        #pragma unroll
        for (int reg = 0; reg < 4; ++reg) {
            float bias = b1[obase + reg];
            float s = 0.0f;
            #pragma unroll
            for (int t = 0; t < 4; ++t) {
                float v = acc[r][t][reg] + bias;
                s += (v > 0.0f ? v : 0.0f);
            }
            s += __shfl_xor(s, 1);
            s += __shfl_xor(s, 2);
            s += __shfl_xor(s, 4);
            s += __shfl_xor(s, 8);
            if (col == 0) out[(size_t)b * OUTC + 64 + obase + reg] = s;
        }
    }
}

extern "C" void kernel_launch(void* const* d_in, const int* in_sizes, int n_in,
                              void* d_out, int out_size, void* d_ws, size_t ws_size,
                              hipStream_t stream) {
    const float* X  = (const float*)d_in[0];
    const float* W0 = (const float*)d_in[1];
    const float* b0 = (const float*)d_in[2];
    const float* W1 = (const float*)d_in[3];
    const float* b1 = (const float*)d_in[4];
    float* out = (float*)d_out;
    __bf16* wbf = (__bf16*)d_ws;  // needs 768 KB

    convert_w_kernel<<<(W0_ELEMS + W1_ELEMS) / 256, 256, 0, stream>>>(W0, W1, wbf);
    cin_kernel<<<BATCH, 256, 0, stream>>>(X, b0, b1, wbf, out);
}

// Round 2
// 160.994 us; speedup vs baseline: 1.6959x; 1.6959x over previous
//
#include <hip/hip_runtime.h>
#include <hip/hip_bf16.h>

// CIN forward: B=2048, F=32, DIM=64, layers (128,128)
// out[b, 0:64]   = sum_d relu(W0 @ z0 + b0)[64:128, d]
// out[b, 64:192] = sum_d relu(W1 @ z1 + b1)[0:128, d]
// z0[h*32+m, d] = x[h,d]*x[m,d]   (h,m in [0,32))
// z1[h*32+m, d] = h1[h,d]*x[m,d]  (h in [0,64), m in [0,32)), h1 = layer0 rows 0..63
//
// R2: f16 MFMA (16x16x32_f16), B-fragment formed by v_pk_mul_f16 broadcast
// multiply (s8 * xv8), W pre-swizzled into fragment order for single-dwordx4
// A loads with immediate offsets.

#define BATCH 2048
#define FSZ   32
#define DIM   64
#define K0    1024
#define K1    2048
#define OUTC  192

#define W0_FRAGS 16384           // 128*1024/8
#define W1_FRAGS 32768           // 128*2048/8
#define W0_ELEMS (128 * K0)      // 131072 f16 elems

typedef _Float16 v8h __attribute__((ext_vector_type(8)));
typedef float    v4f __attribute__((ext_vector_type(4)));

#define XT_PITCH 40   // xT[d][m] pitch (f16): 80B rows, 16B-aligned v8h loads
#define XD_PITCH 66   // xD[m][d] pitch: broadcast-friendly scalar s reads
#define HD_PITCH 66   // h1D[h][d] pitch

// Swizzle W into MFMA A-fragment order (f16):
//   dst[ks*4096 + s*512 + lane*8 + j] = W[(s*16 + (lane&15))*K + ks*32 + (lane>>4)*8 + j]
// so wave w at K-step ks loads fragments for row streams s=2w, 2w+1 at
// base + ks*4096 + 2w*512 + lane*8 (elems), imm offsets {0, 512} elems.
__global__ void convert_w_kernel(const float* __restrict__ W0,
                                 const float* __restrict__ W1,
                                 _Float16* __restrict__ wsw) {
    int t = blockIdx.x * blockDim.x + threadIdx.x;
    if (t < W0_FRAGS) {
        int ks = t >> 9, s = (t >> 6) & 7, lane = t & 63;
        int row = s * 16 + (lane & 15);
        int k0  = ks * 32 + (lane >> 4) * 8;
        const float* src = W0 + (size_t)row * K0 + k0;
        _Float16* dst = wsw + (size_t)t * 8;
        #pragma unroll
        for (int j = 0; j < 8; ++j) dst[j] = (_Float16)src[j];
    } else if (t < W0_FRAGS + W1_FRAGS) {
        int u = t - W0_FRAGS;
        int ks = u >> 9, s = (u >> 6) & 7, lane = u & 63;
        int row = s * 16 + (lane & 15);
        int k0  = ks * 32 + (lane >> 4) * 8;
        const float* src = W1 + (size_t)row * K1 + k0;
        _Float16* dst = wsw + W0_ELEMS + (size_t)u * 8;
        #pragma unroll
        for (int j = 0; j < 8; ++j) dst[j] = (_Float16)src[j];
    }
}

__global__ __launch_bounds__(256, 4) void cin_kernel(
    const float* __restrict__ X,      // (B, 32, 64) fp32
    const float* __restrict__ b0,     // (128,)
    const float* __restrict__ b1,     // (128,)
    const _Float16* __restrict__ Wsw, // swizzled W0 then W1 (f16)
    float* __restrict__ out)          // (B, 192) fp32
{
    __shared__ _Float16 xT[DIM * XT_PITCH];     // xT[d][m] = x[m][d]
    __shared__ _Float16 xD[FSZ * XD_PITCH];     // xD[m][d] = x[m][d]
    __shared__ _Float16 h1D[64 * HD_PITCH];     // h1D[h][d]

    const int b    = blockIdx.x;
    const int tid  = threadIdx.x;
    const int wave = tid >> 6;
    const int lane = tid & 63;
    const int quad = lane >> 4;
    const int col  = lane & 15;

    // ---- stage x -> LDS (both layouts, f16) ----
    const float* xb = X + (size_t)b * (FSZ * DIM);
    #pragma unroll
    for (int i = tid; i < FSZ * DIM; i += 256) {
        int m = i >> 6, d = i & 63;
        _Float16 v = (_Float16)xb[i];
        xT[d * XT_PITCH + m] = v;
        xD[m * XD_PITCH + d] = v;
    }
    __syncthreads();

    // K-invariant packed B vector parts: xv8[t] = x[quad*8 .. quad*8+7][16t+col]
    v8h xv8[4];
    int dd[4];
    #pragma unroll
    for (int t = 0; t < 4; ++t) {
        dd[t] = 16 * t + col;
        xv8[t] = *(const v8h*)(&xT[dd[t] * XT_PITCH + quad * 8]);
    }

    // ================= layer 0 =================
    v4f acc[2][4];
    #pragma unroll
    for (int r = 0; r < 2; ++r)
        #pragma unroll
        for (int t = 0; t < 4; ++t) acc[r][t] = (v4f)0.0f;

    {
        const _Float16* Wk = Wsw + (size_t)wave * 2 * 512 + (size_t)lane * 8;
        #pragma unroll 4
        for (int ks = 0; ks < 32; ++ks) {
            v8h a0 = *(const v8h*)(Wk);
            v8h a1 = *(const v8h*)(Wk + 512);
            Wk += 4096;
            #pragma unroll
            for (int t = 0; t < 4; ++t) {
                _Float16 s = xD[ks * XD_PITCH + dd[t]];
                v8h s8 = {s, s, s, s, s, s, s, s};
                v8h bfr = s8 * xv8[t];
                acc[0][t] = __builtin_amdgcn_mfma_f32_16x16x32_f16(a0, bfr, acc[0][t], 0, 0, 0);
                acc[1][t] = __builtin_amdgcn_mfma_f32_16x16x32_f16(a1, bfr, acc[1][t], 0, 0, 0);
            }
        }
    }

    // ---- epilogue 0: rows 0..63 -> h1D (LDS); rows 64..127 -> out[b, o-64] ----
    #pragma unroll
    for (int r = 0; r < 2; ++r) {
        const int obase = wave * 32 + r * 16 + quad * 4;
        if (obase < 64) {
            #pragma unroll
            for (int reg = 0; reg < 4; ++reg) {
                float bias = b0[obase + reg];
                #pragma unroll
                for (int t = 0; t < 4; ++t) {
                    float v = acc[r][t][reg] + bias;
                    v = v > 0.0f ? v : 0.0f;
                    h1D[(obase + reg) * HD_PITCH + dd[t]] = (_Float16)v;
                }
            }
        } else {
            #pragma unroll
            for (int reg = 0; reg < 4; ++reg) {
                float bias = b0[obase + reg];
                float s = 0.0f;
                #pragma unroll
                for (int t = 0; t < 4; ++t) {
                    float v = acc[r][t][reg] + bias;
                    s += (v > 0.0f ? v : 0.0f);
                }
                s += __shfl_xor(s, 1);
                s += __shfl_xor(s, 2);
                s += __shfl_xor(s, 4);
                s += __shfl_xor(s, 8);
                if (col == 0) out[(size_t)b * OUTC + (obase + reg - 64)] = s;
            }
        }
    }
    __syncthreads();

    // ================= layer 1 =================
    #pragma unroll
    for (int r = 0; r < 2; ++r)
        #pragma unroll
        for (int t = 0; t < 4; ++t) acc[r][t] = (v4f)0.0f;

    {
        const _Float16* Wk = Wsw + W0_ELEMS + (size_t)wave * 2 * 512 + (size_t)lane * 8;
        #pragma unroll 4
        for (int ks = 0; ks < 64; ++ks) {
            v8h a0 = *(const v8h*)(Wk);
            v8h a1 = *(const v8h*)(Wk + 512);
            Wk += 4096;
            #pragma unroll
            for (int t = 0; t < 4; ++t) {
                _Float16 s = h1D[ks * HD_PITCH + dd[t]];
                v8h s8 = {s, s, s, s, s, s, s, s};
                v8h bfr = s8 * xv8[t];
                acc[0][t] = __builtin_amdgcn_mfma_f32_16x16x32_f16(a0, bfr, acc[0][t], 0, 0, 0);
                acc[1][t] = __builtin_amdgcn_mfma_f32_16x16x32_f16(a1, bfr, acc[1][t], 0, 0, 0);
            }
        }
    }

    // ---- epilogue 1: all 128 rows -> out[b, 64+o] ----
    #pragma unroll
    for (int r = 0; r < 2; ++r) {
        const int obase = wave * 32 + r * 16 + quad * 4;
        #pragma unroll
        for (int reg = 0; reg < 4; ++reg) {
            float bias = b1[obase + reg];
            float s = 0.0f;
            #pragma unroll
            for (int t = 0; t < 4; ++t) {
                float v = acc[r][t][reg] + bias;
                s += (v > 0.0f ? v : 0.0f);
            }
            s += __shfl_xor(s, 1);
            s += __shfl_xor(s, 2);
            s += __shfl_xor(s, 4);
            s += __shfl_xor(s, 8);
            if (col == 0) out[(size_t)b * OUTC + 64 + obase + reg] = s;
        }
    }
}

extern "C" void kernel_launch(void* const* d_in, const int* in_sizes, int n_in,
                              void* d_out, int out_size, void* d_ws, size_t ws_size,
                              hipStream_t stream) {
    const float* X  = (const float*)d_in[0];
    const float* W0 = (const float*)d_in[1];
    const float* b0 = (const float*)d_in[2];
    const float* W1 = (const float*)d_in[3];
    const float* b1 = (const float*)d_in[4];
    float* out = (float*)d_out;
    _Float16* wsw = (_Float16*)d_ws;  // needs 768 KB

    convert_w_kernel<<<(W0_FRAGS + W1_FRAGS + 255) / 256, 256, 0, stream>>>(W0, W1, wsw);
    cin_kernel<<<BATCH, 256, 0, stream>>>(X, b0, b1, wsw, out);
}